// Round 12
// baseline (3565.933 us; speedup 1.0000x reference)
//
#include <hip/hip_runtime.h>
#include <stdint.h>
#include <stddef.h>

#define N_AG 81

typedef __bf16 bf16x8 __attribute__((ext_vector_type(8)));
typedef float f32x4 __attribute__((ext_vector_type(4)));
typedef uint32_t u32v4 __attribute__((ext_vector_type(4)));
typedef uint32_t u32v2 __attribute__((ext_vector_type(2)));

// s_par layout (float idx): [0,128) bias, [128,256) ln_gamma, [256,384) ln_beta
#define PB 0
#define PG 128
#define PBT 256

// LDS tile swizzle: byte offset within a 256B (or 128B) row
#define SWZ(row, off) ((uint32_t)(off) ^ (((uint32_t)(row) & 7u) << 4))

__device__ __forceinline__ unsigned short b2u(__bf16 h) {
  return __builtin_bit_cast(unsigned short, h);
}

__device__ __forceinline__ f32x4 f4z() { f32x4 v; v[0]=0.f; v[1]=0.f; v[2]=0.f; v[3]=0.f; return v; }

__device__ __forceinline__ bf16x8 ld_frag(const uint8_t* p) {
  u32v4 v = *(const u32v4*)p;
  return __builtin_bit_cast(bf16x8, v);
}

__device__ __forceinline__ f32x4 mfma16(bf16x8 a, bf16x8 b, f32x4 c) {
  return __builtin_amdgcn_mfma_f32_16x16x32_bf16(a, b, c, 0, 0, 0);
}

// butterfly sum over the 16 lanes of a DPP row (q-dimension); all lanes get the sum.
__device__ __forceinline__ float wave16_sum(float v) {
  v += __builtin_bit_cast(float, __builtin_amdgcn_update_dpp(0, __builtin_bit_cast(int, v), 0xB1, 0xF, 0xF, true));
  v += __builtin_bit_cast(float, __builtin_amdgcn_update_dpp(0, __builtin_bit_cast(int, v), 0x4E, 0xF, 0xF, true));
  v += __builtin_bit_cast(float, __builtin_amdgcn_update_dpp(0, __builtin_bit_cast(int, v), 0x141, 0xF, 0xF, true));
  v += __builtin_bit_cast(float, __builtin_amdgcn_update_dpp(0, __builtin_bit_cast(int, v), 0x140, 0xF, 0xF, true));
  return v;
}

__device__ __forceinline__ bf16x8 mk_frag(const unsigned short (&us)[8]) {
  u32v4 pk;
  pk[0] = (uint32_t)us[0] | ((uint32_t)us[1] << 16);
  pk[1] = (uint32_t)us[2] | ((uint32_t)us[3] << 16);
  pk[2] = (uint32_t)us[4] | ((uint32_t)us[5] << 16);
  pk[3] = (uint32_t)us[6] | ((uint32_t)us[7] << 16);
  return __builtin_bit_cast(bf16x8, pk);
}

// ---- in-block weight staging (raw f32 -> bf16 swizzled LDS images; sources are L2/L3-hot) ----
// s_w1: [o=128][k=64] bf16, 128B rows; k-order: 0..47 glob (W1 rows 10..57), 48..57 zones, pad.
__device__ __forceinline__ void stage_w1(const float* __restrict__ W1, int a,
                                         uint8_t* s_w1, int t) {
  for (int i = t; i < 128 * 64; i += 256) {
    int o = i & 127, kk = i >> 7;
    float v;
    if (kk < 48)      v = W1[((size_t)a * 58 + (10 + kk)) * 128 + o];
    else if (kk < 58) v = W1[((size_t)a * 58 + (kk - 48)) * 128 + o];
    else              v = 0.f;
    uint32_t cb = 2u * kk;
    uint32_t phys = o * 128 + (((cb & ~15u) ^ (((uint32_t)o & 7u) << 4)) | (cb & 15u));
    *(unsigned short*)(s_w1 + phys) = b2u((__bf16)v);
  }
}

// s_w2: [o=128][k=128] bf16, 256B rows
__device__ __forceinline__ void stage_w2(const float* __restrict__ W2, int a,
                                         uint8_t* s_w2, int t) {
  for (int i = t; i < 128 * 128; i += 256) {
    int o = i & 127, kk = i >> 7;
    float v = W2[((size_t)a * 128 + kk) * 128 + o];
    uint32_t cb = 2u * kk;
    uint32_t phys = o * 256 + (((cb & ~15u) ^ (((uint32_t)o & 7u) << 4)) | (cb & 15u));
    *(unsigned short*)(s_w2 + phys) = b2u((__bf16)v);
  }
}

// GEMM1 B-fragment for one batch row (glob part from globimg, zones from zimgT)
__device__ __forceinline__ bf16x8 xfrag(const uint8_t* __restrict__ globimg,
                                        const unsigned short* __restrict__ zimgT,
                                        int brow, int ks, int g,
                                        const int (&nid)[5], int deg) {
  if (ks == 1 && g >= 2) {
    unsigned short us[8];
    if (g == 2) {
      #pragma unroll
      for (int e = 0; e < 5; ++e)
        us[e] = (e < deg) ? zimgT[(size_t)nid[e] * 16384 + brow] : (unsigned short)0;
      #pragma unroll
      for (int e = 0; e < 3; ++e)
        us[5 + e] = (e < deg) ? zimgT[(size_t)(81 + nid[e]) * 16384 + brow] : (unsigned short)0;
    } else {
      us[0] = (3 < deg) ? zimgT[(size_t)(81 + nid[3]) * 16384 + brow] : (unsigned short)0;
      us[1] = (4 < deg) ? zimgT[(size_t)(81 + nid[4]) * 16384 + brow] : (unsigned short)0;
      #pragma unroll
      for (int e = 2; e < 8; ++e) us[e] = 0;
    }
    return mk_frag(us);
  }
  return *(const bf16x8*)(globimg + (size_t)brow * 96 + (32 * ks + 8 * g) * 2);
}

// fused bias + layernorm, 2 batch-cols per lane (pass1 128-row tiles)
__device__ __forceinline__ void bias_ln(f32x4 (&acc)[8][2], const float* s_par, int g) {
  #pragma unroll
  for (int nf = 0; nf < 2; ++nf) {
    float s = 0.f, qs = 0.f;
    #pragma unroll
    for (int mf = 0; mf < 8; ++mf) {
      #pragma unroll
      for (int rg = 0; rg < 4; ++rg) {
        float tv = acc[mf][nf][rg] + s_par[PB + 16 * mf + 4 * g + rg];
        acc[mf][nf][rg] = tv;
        s += tv;
        qs = fmaf(tv, tv, qs);
      }
    }
    s += __shfl_xor(s, 16);  s += __shfl_xor(s, 32);
    qs += __shfl_xor(qs, 16); qs += __shfl_xor(qs, 32);
    float mu = s * (1.f / 128.f);
    float var = qs * (1.f / 128.f) - mu * mu;
    float rstd = rsqrtf(var + 1e-12f);
    #pragma unroll
    for (int mf = 0; mf < 8; ++mf) {
      #pragma unroll
      for (int rg = 0; rg < 4; ++rg) {
        int o = 16 * mf + 4 * g + rg;
        acc[mf][nf][rg] = (acc[mf][nf][rg] - mu) * rstd * s_par[PG + o] + s_par[PBT + o];
      }
    }
  }
}

// fused bias + layernorm, single batch-col per lane (pass2/3 64-row halves)
__device__ __forceinline__ void bias_ln1(f32x4 (&acc)[8], const float* s_par, int g) {
  float s = 0.f, qs = 0.f;
  #pragma unroll
  for (int mf = 0; mf < 8; ++mf) {
    #pragma unroll
    for (int rg = 0; rg < 4; ++rg) {
      float tv = acc[mf][rg] + s_par[PB + 16 * mf + 4 * g + rg];
      acc[mf][rg] = tv;
      s += tv;
      qs = fmaf(tv, tv, qs);
    }
  }
  s += __shfl_xor(s, 16);  s += __shfl_xor(s, 32);
  qs += __shfl_xor(qs, 16); qs += __shfl_xor(qs, 32);
  float mu = s * (1.f / 128.f);
  float var = qs * (1.f / 128.f) - mu * mu;
  float rstd = rsqrtf(var + 1e-12f);
  #pragma unroll
  for (int mf = 0; mf < 8; ++mf) {
    #pragma unroll
    for (int rg = 0; rg < 4; ++rg) {
      int o = 16 * mf + 4 * g + rg;
      acc[mf][rg] = (acc[mf][rg] - mu) * rstd * s_par[PG + o] + s_par[PBT + o];
    }
  }
}

// stats accumulation, 2-col version (pass1)
__device__ __forceinline__ void stats_lds(const f32x4 (&acc)[8][2],
                                          float (&s_red)[2][4][128],
                                          int wv, int g, int q) {
  #pragma unroll
  for (int mf = 0; mf < 8; ++mf) {
    #pragma unroll
    for (int rg = 0; rg < 4; ++rg) {
      float a0v = acc[mf][0][rg], a1v = acc[mf][1][rg];
      float s = a0v + a1v;
      float qq = fmaf(a0v, a0v, a1v * a1v);
      s = wave16_sum(s);
      qq = wave16_sum(qq);
      if (q == 0) {
        int o = 16 * mf + 4 * g + rg;
        s_red[0][wv][o] += s;
        s_red[1][wv][o] += qq;
      }
    }
  }
}

// stats accumulation, 1-col version (pass2)
__device__ __forceinline__ void stats_lds1(const f32x4 (&acc)[8],
                                           float (&s_red)[2][4][128],
                                           int wv, int g, int q) {
  #pragma unroll
  for (int mf = 0; mf < 8; ++mf) {
    #pragma unroll
    for (int rg = 0; rg < 4; ++rg) {
      float s = acc[mf][rg];
      float qq = s * s;
      s = wave16_sum(s);
      qq = wave16_sum(qq);
      if (q == 0) {
        int o = 16 * mf + 4 * g + rg;
        s_red[0][wv][o] += s;
        s_red[1][wv][o] += qq;
      }
    }
  }
}

// h = BN+ReLU(y), bf16-pack into LDS h-tile row 16wv+q (wave-private band)
__device__ __forceinline__ void pack_h(const f32x4 (&acc)[8], const float2* s_bnc,
                                       uint8_t* s_y, int wv, int g, int q) {
  uint32_t row = 16 * wv + q;
  #pragma unroll
  for (int mf = 0; mf < 8; ++mf) {
    unsigned short us[4];
    #pragma unroll
    for (int rg = 0; rg < 4; ++rg) {
      int o = 16 * mf + 4 * g + rg;
      float2 c = s_bnc[o];
      us[rg] = b2u((__bf16)fmaxf(fmaf(acc[mf][rg], c.x, c.y), 0.f));
    }
    u32v2 pk;
    pk[0] = (uint32_t)us[0] | ((uint32_t)us[1] << 16);
    pk[1] = (uint32_t)us[2] | ((uint32_t)us[3] << 16);
    *(u32v2*)(s_y + row * 256 + SWZ(row, 32 * mf + 8 * g)) = pk;
  }
}

// GEMM2 inner: acc2 += (h @ W2)^T for own batch row; B-frag plain (h already BN'd)
__device__ __forceinline__ void gemm2(f32x4 (&acc)[8], const uint8_t* s_y,
                                      const uint8_t* s_w2, int wv, int g, int q) {
  const uint32_t row = 16 * wv + q;
  #pragma unroll
  for (int ks2 = 0; ks2 < 4; ++ks2) {
    bf16x8 hb = ld_frag(s_y + row * 256 + SWZ(row, 64 * ks2 + 16 * g));
    #pragma unroll
    for (int mf = 0; mf < 8; ++mf) {
      uint32_t r = 16 * mf + q;
      uint32_t cb = ((uint32_t)(64 * ks2 + 16 * g)) ^ ((r & 7u) << 4);
      bf16x8 af = ld_frag(s_w2 + r * 256 + cb);
      acc[mf] = mfma16(af, hb, acc[mf]);
    }
  }
}

// ---------- prep kernels ----------
// packed bf16 image of obs[:, :48], 96B per row.
__global__ void prep_obs(const float* __restrict__ obs, uint8_t* __restrict__ globimg) {
  const int row = blockIdx.x * 256 + threadIdx.x;
  if (row >= 16384) return;
  const float* orow = obs + (size_t)row * 210;
  uint8_t* dst = globimg + (size_t)row * 96;
  #pragma unroll
  for (int c = 0; c < 6; ++c) {
    u32v4 pk;
    #pragma unroll
    for (int e = 0; e < 4; ++e) {
      pk[e] = (uint32_t)b2u((__bf16)orow[8 * c + 2 * e]) |
              ((uint32_t)b2u((__bf16)orow[8 * c + 2 * e + 1]) << 16);
    }
    *(u32v4*)(dst + 16 * c) = pk;
  }
}

// transposed bf16 zone image: zimgT[n][b], n in [0,162) = obs cols 48..209.
__global__ void prep_zimgT(const float* __restrict__ obs, unsigned short* __restrict__ zimgT) {
  __shared__ unsigned short lt[128][164];
  const int t = threadIdx.x;
  const int b0 = blockIdx.x * 128;
  for (int i = t; i < 128 * 162; i += 256) {
    int br = i / 162, n = i - 162 * br;
    lt[br][n] = b2u((__bf16)obs[(size_t)(b0 + br) * 210 + 48 + n]);
  }
  __syncthreads();
  for (int i = t; i < 162 * 128; i += 256) {
    int n = i >> 7, br = i & 127;
    zimgT[(size_t)n * 16384 + b0 + br] = lt[br][n];
  }
}

// finalize BN coefs from atomic sums: bn = {rs, beta - mu*rs}
__global__ void reduce_bn(const float* __restrict__ S, const float* __restrict__ Q,
                          const float* __restrict__ beta, float2* __restrict__ bn) {
  const int a = blockIdx.x, k = threadIdx.x;
  float mu = S[a * 128 + k] * (1.f / 16384.f);
  float var = Q[a * 128 + k] * (1.f / 16384.f) - mu * mu;
  float rs = rsqrtf(var + 1e-3f);  // BN_EPS
  bn[a * 128 + k] = make_float2(rs, beta[a * 128 + k] - mu * rs);
}

// ---------- pass 1: GEMM1 + LN1 -> BN1 stats only (no y write, no in-loop barriers) ----------
__launch_bounds__(256, 4)
__global__ void pass1_kernel(const int* __restrict__ nidx,
                             const float* __restrict__ b1, const float* __restrict__ ln1g,
                             const float* __restrict__ ln1b,
                             const float* __restrict__ W1,
                             const uint8_t* __restrict__ globimg,
                             const unsigned short* __restrict__ zimgT,
                             float* __restrict__ statS, float* __restrict__ statQ) {
  __shared__ __align__(16) uint8_t s_w1[16384];
  __shared__ float s_par[384];
  __shared__ float s_red[2][4][128];

  const int t = threadIdx.x;
  const int wv = t >> 6, l = t & 63, g = l >> 4, q = l & 15;
  const int a = blockIdx.x % N_AG;
  const int sub = blockIdx.x / N_AG;

  const int r9 = a / 9, c9 = a - 9 * r9;
  const int deg = 1 + (r9 > 0) + (r9 < 8) + (c9 > 0) + (c9 < 8);
  int nid[5];
  #pragma unroll
  for (int d = 0; d < 5; ++d) nid[d] = __builtin_amdgcn_readfirstlane(nidx[a * 5 + d]);

  stage_w1(W1, a, s_w1, t);
  if (t < 128) {
    s_par[PB + t] = b1[a * 128 + t];
    s_par[PG + t] = ln1g[a * 128 + t];
    s_par[PBT + t] = ln1b[a * 128 + t];
  }
  #pragma unroll
  for (int i = 0; i < 4; ++i) ((float*)s_red)[t + 256 * i] = 0.f;
  __syncthreads();

  for (int tt = 0; tt < 4; ++tt) {
    const int tile = sub * 4 + tt;

    bf16x8 bfr[2][2];
    #pragma unroll
    for (int ks = 0; ks < 2; ++ks) {
      #pragma unroll
      for (int nf = 0; nf < 2; ++nf) {
        const int brow = tile * 128 + 32 * wv + 16 * nf + q;
        bfr[ks][nf] = xfrag(globimg, zimgT, brow, ks, g, nid, deg);
      }
    }

    f32x4 acc[8][2];
    #pragma unroll
    for (int mf = 0; mf < 8; ++mf) { acc[mf][0] = f4z(); acc[mf][1] = f4z(); }
    #pragma unroll
    for (int ks = 0; ks < 2; ++ks) {
      #pragma unroll
      for (int mf = 0; mf < 8; ++mf) {
        uint32_t r = 16 * mf + q;
        uint32_t cb = ((uint32_t)(64 * ks + 16 * g)) ^ ((r & 7u) << 4);
        bf16x8 af = ld_frag(s_w1 + r * 128 + cb);
        acc[mf][0] = mfma16(af, bfr[ks][0], acc[mf][0]);
        acc[mf][1] = mfma16(af, bfr[ks][1], acc[mf][1]);
      }
    }

    bias_ln(acc, s_par, g);
    stats_lds(acc, s_red, wv, g, q);
  }

  __syncthreads();
  if (t < 128) {
    float S = s_red[0][0][t] + s_red[0][1][t] + s_red[0][2][t] + s_red[0][3][t];
    float Q = s_red[1][0][t] + s_red[1][1][t] + s_red[1][2][t] + s_red[1][3][t];
    atomicAdd(statS + a * 128 + t, S);
    atomicAdd(statQ + a * 128 + t, Q);
  }
}

// ---------- pass 2: recompute GEMM1 -> h1(LDS) -> GEMM2 + LN2 -> BN2 stats (no y traffic) ----------
__launch_bounds__(256, 2)
__global__ void pass2_kernel(const int* __restrict__ nidx,
                             const float* __restrict__ b1, const float* __restrict__ ln1g,
                             const float* __restrict__ ln1b,
                             const float* __restrict__ b2, const float* __restrict__ ln2g,
                             const float* __restrict__ ln2b,
                             const float* __restrict__ W1, const float* __restrict__ W2,
                             const uint8_t* __restrict__ globimg,
                             const unsigned short* __restrict__ zimgT,
                             const float2* __restrict__ bn1,
                             float* __restrict__ statS, float* __restrict__ statQ) {
  __shared__ __align__(16) uint8_t s_w1[16384];
  __shared__ __align__(16) uint8_t s_w2[32768];
  __shared__ __align__(16) uint8_t s_y[16384];
  __shared__ float s_parA[384];
  __shared__ float s_parB[384];
  __shared__ __align__(16) float2 s_bnc1[128];
  __shared__ float s_red[2][4][128];

  const int t = threadIdx.x;
  const int wv = t >> 6, l = t & 63, g = l >> 4, q = l & 15;
  const int a = blockIdx.x % N_AG;
  const int sub = blockIdx.x / N_AG;

  const int r9 = a / 9, c9 = a - 9 * r9;
  const int deg = 1 + (r9 > 0) + (r9 < 8) + (c9 > 0) + (c9 < 8);
  int nid[5];
  #pragma unroll
  for (int d = 0; d < 5; ++d) nid[d] = __builtin_amdgcn_readfirstlane(nidx[a * 5 + d]);

  stage_w1(W1, a, s_w1, t);
  stage_w2(W2, a, s_w2, t);
  if (t < 128) {
    s_parA[PB + t] = b1[a * 128 + t];
    s_parA[PG + t] = ln1g[a * 128 + t];
    s_parA[PBT + t] = ln1b[a * 128 + t];
    s_parB[PB + t] = b2[a * 128 + t];
    s_parB[PG + t] = ln2g[a * 128 + t];
    s_parB[PBT + t] = ln2b[a * 128 + t];
    s_bnc1[t] = bn1[a * 128 + t];
  }
  #pragma unroll
  for (int i = 0; i < 4; ++i) ((float*)s_red)[t + 256 * i] = 0.f;
  __syncthreads();

  for (int hh = 0; hh < 8; ++hh) {
    const int brow = sub * 512 + hh * 64 + 16 * wv + q;

    bf16x8 bfr0 = xfrag(globimg, zimgT, brow, 0, g, nid, deg);
    bf16x8 bfr1 = xfrag(globimg, zimgT, brow, 1, g, nid, deg);

    f32x4 acc1[8];
    #pragma unroll
    for (int mf = 0; mf < 8; ++mf) acc1[mf] = f4z();
    #pragma unroll
    for (int ks = 0; ks < 2; ++ks) {
      bf16x8 bx = (ks == 0) ? bfr0 : bfr1;
      #pragma unroll
      for (int mf = 0; mf < 8; ++mf) {
        uint32_t r = 16 * mf + q;
        uint32_t cb = ((uint32_t)(64 * ks + 16 * g)) ^ ((r & 7u) << 4);
        bf16x8 af = ld_frag(s_w1 + r * 128 + cb);
        acc1[mf] = mfma16(af, bx, acc1[mf]);
      }
    }
    bias_ln1(acc1, s_parA, g);
    pack_h(acc1, s_bnc1, s_y, wv, g, q);   // own band; in-wave ordering suffices

    f32x4 acc2[8];
    #pragma unroll
    for (int mf = 0; mf < 8; ++mf) acc2[mf] = f4z();
    gemm2(acc2, s_y, s_w2, wv, g, q);
    bias_ln1(acc2, s_parB, g);
    stats_lds1(acc2, s_red, wv, g, q);
  }

  __syncthreads();
  if (t < 128) {
    float S = s_red[0][0][t] + s_red[0][1][t] + s_red[0][2][t] + s_red[0][3][t];
    float Q = s_red[1][0][t] + s_red[1][1][t] + s_red[1][2][t] + s_red[1][3][t];
    atomicAdd(statS + a * 128 + t, S);
    atomicAdd(statQ + a * 128 + t, Q);
  }
}

// ---------- pass 3: recompute GEMM1+GEMM2 -> h2 -> GEMM3 -> softmax -> dense output ----------
__launch_bounds__(256, 2)
__global__ void pass3_kernel(const int* __restrict__ nidx,
                             const float* __restrict__ b1, const float* __restrict__ ln1g,
                             const float* __restrict__ ln1b,
                             const float* __restrict__ b2, const float* __restrict__ ln2g,
                             const float* __restrict__ ln2b,
                             const float* __restrict__ boutp, const float* __restrict__ Wout,
                             const float* __restrict__ W1, const float* __restrict__ W2,
                             const uint8_t* __restrict__ globimg,
                             const unsigned short* __restrict__ zimgT,
                             const float2* __restrict__ bn1, const float2* __restrict__ bn2,
                             float* __restrict__ out) {
  __shared__ __align__(16) uint8_t s_w1[16384];
  __shared__ __align__(16) uint8_t s_w2[32768];
  __shared__ __align__(16) uint8_t s_y[16384];
  __shared__ float s_parA[384];
  __shared__ float s_parB[384];
  __shared__ __align__(16) float2 s_bnc1[128];
  __shared__ __align__(16) float2 s_bnc2[128];
  __shared__ float s_p[4][16][6];
  __shared__ int s_inv[81];
  __shared__ float s_bout[16];

  const int t = threadIdx.x;
  const int wv = t >> 6, l = t & 63, g = l >> 4, q = l & 15;
  const int a = blockIdx.x % N_AG;
  const int sub = blockIdx.x / N_AG;

  const int r9 = a / 9, c9 = a - 9 * r9;
  const int deg = 1 + (r9 > 0) + (r9 < 8) + (c9 > 0) + (c9 < 8);
  int nid[5];
  #pragma unroll
  for (int d = 0; d < 5; ++d) nid[d] = __builtin_amdgcn_readfirstlane(nidx[a * 5 + d]);

  stage_w1(W1, a, s_w1, t);
  stage_w2(W2, a, s_w2, t);
  if (t < 128) {
    s_parA[PB + t] = b1[a * 128 + t];
    s_parA[PG + t] = ln1g[a * 128 + t];
    s_parA[PBT + t] = ln1b[a * 128 + t];
    s_parB[PB + t] = b2[a * 128 + t];
    s_parB[PG + t] = ln2g[a * 128 + t];
    s_parB[PBT + t] = ln2b[a * 128 + t];
    s_bnc1[t] = bn1[a * 128 + t];
    s_bnc2[t] = bn2[a * 128 + t];
  }
  if (t < 16) s_bout[t] = (t < 5) ? boutp[a * 5 + t] : 0.f;
  if (t < 81) {
    int v = -1;
    #pragma unroll
    for (int d = 0; d < 5; ++d)
      if (d < deg && nid[d] == t) v = d;
    s_inv[t] = v;
  }

  // Wout A-frags direct to regs (Wout is 265KB total, L2/L3-hot; once per block)
  bf16x8 afr[4];
  #pragma unroll
  for (int ks2 = 0; ks2 < 4; ++ks2) {
    unsigned short us[8];
    #pragma unroll
    for (int e = 0; e < 8; ++e) {
      int k = 32 * ks2 + 8 * g + e;
      us[e] = (q < 5) ? b2u((__bf16)Wout[((size_t)a * 128 + k) * 5 + q]) : (unsigned short)0;
    }
    afr[ks2] = mk_frag(us);
  }
  __syncthreads();

  for (int hh = 0; hh < 8; ++hh) {
    const int base = sub * 512 + hh * 64;
    const int brow = base + 16 * wv + q;

    bf16x8 bfr0 = xfrag(globimg, zimgT, brow, 0, g, nid, deg);
    bf16x8 bfr1 = xfrag(globimg, zimgT, brow, 1, g, nid, deg);

    f32x4 acc1[8];
    #pragma unroll
    for (int mf = 0; mf < 8; ++mf) acc1[mf] = f4z();
    #pragma unroll
    for (int ks = 0; ks < 2; ++ks) {
      bf16x8 bx = (ks == 0) ? bfr0 : bfr1;
      #pragma unroll
      for (int mf = 0; mf < 8; ++mf) {
        uint32_t r = 16 * mf + q;
        uint32_t cb = ((uint32_t)(64 * ks + 16 * g)) ^ ((r & 7u) << 4);
        bf16x8 af = ld_frag(s_w1 + r * 128 + cb);
        acc1[mf] = mfma16(af, bx, acc1[mf]);
      }
    }
    bias_ln1(acc1, s_parA, g);
    pack_h(acc1, s_bnc1, s_y, wv, g, q);

    f32x4 acc2[8];
    #pragma unroll
    for (int mf = 0; mf < 8; ++mf) acc2[mf] = f4z();
    gemm2(acc2, s_y, s_w2, wv, g, q);
    bias_ln1(acc2, s_parB, g);
    pack_h(acc2, s_bnc2, s_y, wv, g, q);   // overwrite own band with h2 (own reads done)

    // GEMM3: logits^T (rows d=4g+rg, col = own batch row)
    f32x4 accd = f4z();
    {
      const uint32_t row = 16 * wv + q;
      #pragma unroll
      for (int ks2 = 0; ks2 < 4; ++ks2) {
        bf16x8 hb = ld_frag(s_y + row * 256 + SWZ(row, 64 * ks2 + 16 * g));
        accd = mfma16(afr[ks2], hb, accd);
      }
    }
    #pragma unroll
    for (int rg = 0; rg < 4; ++rg) accd[rg] += s_bout[4 * g + rg];
    float d4 = __shfl_xor(accd[0], 16);

    float p[5];
    {
      float v[5] = {accd[0], accd[1], accd[2], accd[3], d4};
      float mx = v[0];
      #pragma unroll
      for (int d = 1; d < 5; ++d)
        if (d < deg) mx = fmaxf(mx, v[d]);
      float den = 0.f;
      #pragma unroll
      for (int d = 0; d < 5; ++d) {
        float e = (d < deg) ? __expf(v[d] - mx) : 0.f;
        p[d] = e;
        den += e;
      }
      float inv = 1.f / den;
      #pragma unroll
      for (int d = 0; d < 5; ++d) p[d] *= inv;
    }

    if (g == 0) {
      #pragma unroll
      for (int d = 0; d < 5; ++d) s_p[wv][q][d] = p[d];
    }

    // per-wave dense output store: own 16 rows x 81, zeros expanded via s_inv
    const size_t orow_base = (size_t)(base + 16 * wv) * 6561 + (size_t)a * 81;
    for (int i = l; i < 16 * 81; i += 64) {
      int r16 = i / 81;
      int n = i - 81 * r16;
      int d = s_inv[n];
      float val = (d >= 0) ? s_p[wv][r16][d] : 0.f;
      out[orow_base + (size_t)r16 * 6561 + n] = val;
    }
  }
}

extern "C" void kernel_launch(void* const* d_in, const int* in_sizes, int n_in,
                              void* d_out, int out_size, void* d_ws, size_t ws_size,
                              hipStream_t stream) {
  (void)in_sizes; (void)n_in; (void)out_size; (void)ws_size;
  const float* obs = (const float*)d_in[0];
  const int* nidx = (const int*)d_in[1];
  // d_in[2] = neigh_mask (derived structurally)
  const float* W1 = (const float*)d_in[3];
  const float* b1 = (const float*)d_in[4];
  const float* ln1g = (const float*)d_in[5];
  const float* ln1b = (const float*)d_in[6];
  const float* bnb1 = (const float*)d_in[7];
  const float* W2 = (const float*)d_in[8];
  const float* b2 = (const float*)d_in[9];
  const float* ln2g = (const float*)d_in[10];
  const float* ln2b = (const float*)d_in[11];
  const float* bnb2 = (const float*)d_in[12];
  const float* Wout = (const float*)d_in[13];
  const float* bout = (const float*)d_in[14];
  float* out = (float*)d_out;
  uint8_t* ws = (uint8_t*)d_ws;

  uint8_t* globimg = ws;                             // 1,572,864
  unsigned short* zimgT = (unsigned short*)(ws + 1572864);  // 5,308,416
  float* statS1 = (float*)(ws + 6881280);            // 41,472 each, 4 contiguous
  float* statQ1 = (float*)(ws + 6922752);
  float* statS2 = (float*)(ws + 6964224);
  float* statQ2 = (float*)(ws + 7005696);
  float2* bn1 = (float2*)(ws + 7047168);             // 82,944
  float2* bn2 = (float2*)(ws + 7130112);             // 82,944
  // total ws use: 7,213,056 B (< 8,457,216 proven available)

  prep_obs<<<64, 256, 0, stream>>>(obs, globimg);
  prep_zimgT<<<128, 256, 0, stream>>>(obs, zimgT);
  hipMemsetAsync(statS1, 0, 4 * 41472, stream);

  pass1_kernel<<<N_AG * 32, 256, 0, stream>>>(nidx, b1, ln1g, ln1b, W1, globimg, zimgT,
                                              statS1, statQ1);
  reduce_bn<<<N_AG, 128, 0, stream>>>(statS1, statQ1, bnb1, bn1);

  pass2_kernel<<<N_AG * 32, 256, 0, stream>>>(nidx, b1, ln1g, ln1b, b2, ln2g, ln2b,
                                              W1, W2, globimg, zimgT, bn1, statS2, statQ2);
  reduce_bn<<<N_AG, 128, 0, stream>>>(statS2, statQ2, bnb2, bn2);

  pass3_kernel<<<N_AG * 32, 256, 0, stream>>>(nidx, b1, ln1g, ln1b, b2, ln2g, ln2b,
                                              bout, Wout, W1, W2, globimg, zimgT,
                                              bn1, bn2, out);
}

// Round 13
// 757.210 us; speedup vs baseline: 4.7093x; 4.7093x over previous
//
#include <hip/hip_runtime.h>
#include <stdint.h>
#include <stddef.h>

#define N_AG 81

typedef __bf16 bf16x8 __attribute__((ext_vector_type(8)));
typedef float f32x4 __attribute__((ext_vector_type(4)));
typedef uint32_t u32v4 __attribute__((ext_vector_type(4)));
typedef uint32_t u32v2 __attribute__((ext_vector_type(2)));

// s_par layout (float idx): [0,128) bias, [128,256) ln_gamma, [256,384) ln_beta
#define PB 0
#define PG 128
#define PBT 256

// LDS y-tile swizzle: linear byte offset 'off' within a 256B row
#define SWZ(row, off) ((uint32_t)(off) ^ (((uint32_t)(row) & 7u) << 4))

__device__ __forceinline__ unsigned short b2u(__bf16 h) {
  return __builtin_bit_cast(unsigned short, h);
}

__device__ __forceinline__ f32x4 f4z() { f32x4 v; v[0]=0.f; v[1]=0.f; v[2]=0.f; v[3]=0.f; return v; }

__device__ __forceinline__ bf16x8 ld_frag(const uint8_t* p) {
  u32v4 v = *(const u32v4*)p;
  return __builtin_bit_cast(bf16x8, v);
}

__device__ __forceinline__ f32x4 mfma16(bf16x8 a, bf16x8 b, f32x4 c) {
  return __builtin_amdgcn_mfma_f32_16x16x32_bf16(a, b, c, 0, 0, 0);
}

// XCD-chunked work mapping: each XCD (round-robin dispatch, bid%8) owns a contiguous
// 324-block chunk = 4 subs x 81 agents -> y/out lines stay XCD-local, rows dense.
__device__ __forceinline__ void work_id(int bid, int& a, int& sub) {
  int w = (bid & 7) * 324 + (bid >> 3);
  a = w % N_AG;
  sub = w / N_AG;
}

// y slot for (batch row b, agent a): 256B window inside out[b][a][:], 64B-aligned.
__device__ __forceinline__ uint8_t* yslot(float* out, int b, int a) {
  size_t base = (size_t)b * 26244 + (size_t)a * 324;
  uint32_t pad = (uint32_t)(64 - (base & 63)) & 63u;
  return (uint8_t*)out + base + pad;
}

// butterfly sum over the 16 lanes of a DPP row (q-dimension); all lanes get the sum.
__device__ __forceinline__ float wave16_sum(float v) {
  v += __builtin_bit_cast(float, __builtin_amdgcn_update_dpp(0, __builtin_bit_cast(int, v), 0xB1, 0xF, 0xF, true));
  v += __builtin_bit_cast(float, __builtin_amdgcn_update_dpp(0, __builtin_bit_cast(int, v), 0x4E, 0xF, 0xF, true));
  v += __builtin_bit_cast(float, __builtin_amdgcn_update_dpp(0, __builtin_bit_cast(int, v), 0x141, 0xF, 0xF, true));
  v += __builtin_bit_cast(float, __builtin_amdgcn_update_dpp(0, __builtin_bit_cast(int, v), 0x140, 0xF, 0xF, true));
  return v;
}

__device__ __forceinline__ bf16x8 mk_frag(const unsigned short (&us)[8]) {
  u32v4 pk;
  pk[0] = (uint32_t)us[0] | ((uint32_t)us[1] << 16);
  pk[1] = (uint32_t)us[2] | ((uint32_t)us[3] << 16);
  pk[2] = (uint32_t)us[4] | ((uint32_t)us[5] << 16);
  pk[3] = (uint32_t)us[6] | ((uint32_t)us[7] << 16);
  return __builtin_bit_cast(bf16x8, pk);
}

// BN+ReLU applied to 8 bf16 y-values (one 16B word) with packed (scale,shift) coefs.
__device__ __forceinline__ bf16x8 bn_frag(u32v4 yv, const f32x4 (&cf)[4]) {
  bf16x8 r;
  #pragma unroll
  for (int j = 0; j < 8; ++j) {
    uint32_t us = (j & 1) ? (yv[j >> 1] >> 16) : (yv[j >> 1] & 0xffffu);
    float f = __builtin_bit_cast(float, us << 16);
    float h = fmaf(f, cf[j >> 1][(j & 1) * 2], cf[j >> 1][(j & 1) * 2 + 1]);
    r[j] = (__bf16)fmaxf(h, 0.f);
  }
  return r;
}

// fused bias + layernorm (single-pass sums, var = E[x^2] - mu^2)
__device__ __forceinline__ void bias_ln(f32x4 (&acc)[8][2], const float* s_par, int g) {
  #pragma unroll
  for (int nf = 0; nf < 2; ++nf) {
    float s = 0.f, qs = 0.f;
    #pragma unroll
    for (int mf = 0; mf < 8; ++mf) {
      #pragma unroll
      for (int rg = 0; rg < 4; ++rg) {
        float tv = acc[mf][nf][rg] + s_par[PB + 16 * mf + 4 * g + rg];
        acc[mf][nf][rg] = tv;
        s += tv;
        qs = fmaf(tv, tv, qs);
      }
    }
    s += __shfl_xor(s, 16);  s += __shfl_xor(s, 32);
    qs += __shfl_xor(qs, 16); qs += __shfl_xor(qs, 32);
    float mu = s * (1.f / 128.f);
    float var = qs * (1.f / 128.f) - mu * mu;
    float rstd = rsqrtf(var + 1e-12f);
    #pragma unroll
    for (int mf = 0; mf < 8; ++mf) {
      #pragma unroll
      for (int rg = 0; rg < 4; ++rg) {
        int o = 16 * mf + 4 * g + rg;
        acc[mf][nf][rg] = (acc[mf][nf][rg] - mu) * rstd * s_par[PG + o] + s_par[PBT + o];
      }
    }
  }
}

// per-wave BN-stat accumulation into LDS: DPP butterfly over q lanes, q==0 RMW own wave row.
__device__ __forceinline__ void stats_lds(const f32x4 (&acc)[8][2],
                                          float (&s_red)[2][4][128],
                                          int wv, int g, int q) {
  #pragma unroll
  for (int mf = 0; mf < 8; ++mf) {
    #pragma unroll
    for (int rg = 0; rg < 4; ++rg) {
      float a0v = acc[mf][0][rg], a1v = acc[mf][1][rg];
      float s = a0v + a1v;
      float qq = fmaf(a0v, a0v, a1v * a1v);
      s = wave16_sum(s);
      qq = wave16_sum(qq);
      if (q == 0) {
        int o = 16 * mf + 4 * g + rg;
        s_red[0][wv][o] += s;
        s_red[1][wv][o] += qq;
      }
    }
  }
}

// pack accumulator tile (bf16) into LDS y-tile (swizzled acc layout); wave-private band.
__device__ __forceinline__ void pack_lds(const f32x4 (&acc)[8][2], uint8_t* s_y,
                                         int wv, int g, int q) {
  #pragma unroll
  for (int nf = 0; nf < 2; ++nf) {
    uint32_t row = 32 * wv + 16 * nf + q;
    #pragma unroll
    for (int mf = 0; mf < 8; ++mf) {
      u32v2 pk;
      pk[0] = (uint32_t)b2u((__bf16)acc[mf][nf][0]) | ((uint32_t)b2u((__bf16)acc[mf][nf][1]) << 16);
      pk[1] = (uint32_t)b2u((__bf16)acc[mf][nf][2]) | ((uint32_t)b2u((__bf16)acc[mf][nf][3]) << 16);
      *(u32v2*)(s_y + row * 256 + SWZ(row, 32 * mf + 8 * g)) = pk;
    }
  }
}

// burst copy LDS y-tile -> global slots (thread: one contiguous 128B half-slot; own band)
__device__ __forceinline__ void burst_out(const uint8_t* s_y, float* out, int tile, int a, int t) {
  const int row = t >> 1, half = t & 1;
  uint8_t* sp = yslot(out, tile * 128 + row, a) + half * 128;
  #pragma unroll
  for (int j = 0; j < 8; ++j) {
    u32v4 v = *(const u32v4*)(s_y + row * 256 + SWZ(row, half * 128 + 16 * j));
    *(u32v4*)(sp + 16 * j) = v;
  }
}

// burst copy global slots -> LDS y-tile (own band)
__device__ __forceinline__ void burst_in(uint8_t* s_y, float* out, int tile, int a, int t) {
  const int row = t >> 1, half = t & 1;
  const uint8_t* sp = yslot(out, tile * 128 + row, a) + half * 128;
  #pragma unroll
  for (int j = 0; j < 8; ++j) {
    u32v4 v = *(const u32v4*)(sp + 16 * j);
    *(u32v4*)(s_y + row * 256 + SWZ(row, half * 128 + 16 * j)) = v;
  }
}

// ---------- prep kernels ----------
__global__ void prep_w1(const float* __restrict__ W1, uint8_t* __restrict__ w1img) {
  const int a = blockIdx.x, t = threadIdx.x;
  for (int i = t; i < 128 * 64; i += 256) {
    int o = i & 127, kk = i >> 7;
    float v;
    if (kk < 48)      v = W1[((size_t)a * 58 + (10 + kk)) * 128 + o];
    else if (kk < 58) v = W1[((size_t)a * 58 + (kk - 48)) * 128 + o];
    else              v = 0.f;
    uint32_t cb = 2u * kk;
    uint32_t phys = o * 128 + (((cb & ~15u) ^ (((uint32_t)o & 7u) << 4)) | (cb & 15u));
    *(unsigned short*)(w1img + (size_t)a * 16384 + phys) = b2u((__bf16)v);
  }
}

__global__ void prep_w2wo(const float* __restrict__ W2, const float* __restrict__ Wout,
                          uint8_t* __restrict__ w2img, uint8_t* __restrict__ woimg) {
  const int a = blockIdx.x, t = threadIdx.x;
  for (int i = t; i < 128 * 128; i += 256) {
    int o = i & 127, kk = i >> 7;
    float v = W2[((size_t)a * 128 + kk) * 128 + o];
    uint32_t cb = 2u * kk;
    uint32_t phys = o * 256 + (((cb & ~15u) ^ (((uint32_t)o & 7u) << 4)) | (cb & 15u));
    *(unsigned short*)(w2img + (size_t)a * 32768 + phys) = b2u((__bf16)v);
  }
  for (int i = t; i < 16 * 128; i += 256) {
    int k = i & 127, d = i >> 7;
    float v = (d < 5) ? Wout[((size_t)a * 128 + k) * 5 + d] : 0.f;
    uint32_t cb = 2u * k;
    uint32_t phys = d * 256 + (((cb & ~15u) ^ (((uint32_t)d & 7u) << 4)) | (cb & 15u));
    *(unsigned short*)(woimg + (size_t)a * 4096 + phys) = b2u((__bf16)v);
  }
}

__global__ void prep_obs(const float* __restrict__ obs, uint8_t* __restrict__ globimg) {
  const int row = blockIdx.x * 256 + threadIdx.x;
  if (row >= 16384) return;
  const float* orow = obs + (size_t)row * 210;
  uint8_t* dst = globimg + (size_t)row * 96;
  #pragma unroll
  for (int c = 0; c < 6; ++c) {
    u32v4 pk;
    #pragma unroll
    for (int e = 0; e < 4; ++e) {
      pk[e] = (uint32_t)b2u((__bf16)orow[8 * c + 2 * e]) |
              ((uint32_t)b2u((__bf16)orow[8 * c + 2 * e + 1]) << 16);
    }
    *(u32v4*)(dst + 16 * c) = pk;
  }
}

// transposed bf16 zone image: zimgT[n][b], n in [0,162) = obs cols 48..209.
__global__ void prep_zimgT(const float* __restrict__ obs, unsigned short* __restrict__ zimgT) {
  __shared__ unsigned short lt[128][164];
  const int t = threadIdx.x;
  const int b0 = blockIdx.x * 128;
  for (int i = t; i < 128 * 162; i += 256) {
    int br = i / 162, n = i - 162 * br;
    lt[br][n] = b2u((__bf16)obs[(size_t)(b0 + br) * 210 + 48 + n]);
  }
  __syncthreads();
  for (int i = t; i < 162 * 128; i += 256) {
    int n = i >> 7, br = i & 127;
    zimgT[(size_t)n * 16384 + b0 + br] = lt[br][n];
  }
}

// finalize BN coefs from atomic sums: bn = {rs, beta - mu*rs}
__global__ void reduce_bn(const float* __restrict__ S, const float* __restrict__ Q,
                          const float* __restrict__ beta, float2* __restrict__ bn) {
  const int a = blockIdx.x, k = threadIdx.x;
  float mu = S[a * 128 + k] * (1.f / 16384.f);
  float var = Q[a * 128 + k] * (1.f / 16384.f) - mu * mu;
  float rs = rsqrtf(var + 1e-3f);  // BN_EPS
  bn[a * 128 + k] = make_float2(rs, beta[a * 128 + k] - mu * rs);
}

// ---------- pass 1: GEMM1 + LN1 -> y1 slots + BN1 stats (1 barrier/tile) ----------
__launch_bounds__(256, 2)
__global__ void pass1_kernel(const int* __restrict__ nidx,
                             const float* __restrict__ b1, const float* __restrict__ ln1g,
                             const float* __restrict__ ln1b,
                             const uint8_t* __restrict__ w1img,
                             const uint8_t* __restrict__ globimg,
                             const unsigned short* __restrict__ zimgT,
                             float* __restrict__ statS, float* __restrict__ statQ,
                             float* __restrict__ out) {
  __shared__ __align__(16) uint8_t s_w1[16384];
  __shared__ __align__(16) uint8_t s_y[32768];
  __shared__ float s_par[384];
  __shared__ float s_red[2][4][128];

  const int t = threadIdx.x;
  const int wv = t >> 6, l = t & 63, g = l >> 4, q = l & 15;
  int a, sub;
  work_id(blockIdx.x, a, sub);

  const int r9 = a / 9, c9 = a - 9 * r9;
  const int deg = 1 + (r9 > 0) + (r9 < 8) + (c9 > 0) + (c9 < 8);
  int nid[5];
  #pragma unroll
  for (int d = 0; d < 5; ++d) nid[d] = __builtin_amdgcn_readfirstlane(nidx[a * 5 + d]);

  const uint8_t* w1src = w1img + (size_t)a * 16384;
  #pragma unroll
  for (int i = 0; i < 4; ++i) ((u32v4*)s_w1)[t + 256 * i] = ((const u32v4*)w1src)[t + 256 * i];
  if (t < 128) {
    s_par[PB + t] = b1[a * 128 + t];
    s_par[PG + t] = ln1g[a * 128 + t];
    s_par[PBT + t] = ln1b[a * 128 + t];
  }
  #pragma unroll
  for (int i = 0; i < 4; ++i) ((float*)s_red)[t + 256 * i] = 0.f;
  __syncthreads();

  for (int tt = 0; tt < 4; ++tt) {
    const int tile = sub * 4 + tt;

    bf16x8 bfr[2][2];
    #pragma unroll
    for (int ks = 0; ks < 2; ++ks) {
      #pragma unroll
      for (int nf = 0; nf < 2; ++nf) {
        const int brow = tile * 128 + 32 * wv + 16 * nf + q;
        if (ks == 1 && g >= 2) {
          unsigned short us[8];
          if (g == 2) {
            #pragma unroll
            for (int e = 0; e < 5; ++e)
              us[e] = (e < deg) ? zimgT[(size_t)nid[e] * 16384 + brow] : (unsigned short)0;
            #pragma unroll
            for (int e = 0; e < 3; ++e)
              us[5 + e] = (e < deg) ? zimgT[(size_t)(81 + nid[e]) * 16384 + brow] : (unsigned short)0;
          } else {
            us[0] = (3 < deg) ? zimgT[(size_t)(81 + nid[3]) * 16384 + brow] : (unsigned short)0;
            us[1] = (4 < deg) ? zimgT[(size_t)(81 + nid[4]) * 16384 + brow] : (unsigned short)0;
            #pragma unroll
            for (int e = 2; e < 8; ++e) us[e] = 0;
          }
          bfr[ks][nf] = mk_frag(us);
        } else {
          bfr[ks][nf] = *(const bf16x8*)(globimg + (size_t)brow * 96 + (32 * ks + 8 * g) * 2);
        }
      }
    }

    f32x4 acc[8][2];
    #pragma unroll
    for (int mf = 0; mf < 8; ++mf) { acc[mf][0] = f4z(); acc[mf][1] = f4z(); }
    #pragma unroll
    for (int ks = 0; ks < 2; ++ks) {
      #pragma unroll
      for (int mf = 0; mf < 8; ++mf) {
        uint32_t r = 16 * mf + q;
        uint32_t cb = ((uint32_t)(64 * ks + 16 * g)) ^ ((r & 7u) << 4);
        bf16x8 af = ld_frag(s_w1 + r * 128 + cb);
        acc[mf][0] = mfma16(af, bfr[ks][0], acc[mf][0]);
        acc[mf][1] = mfma16(af, bfr[ks][1], acc[mf][1]);
      }
    }

    bias_ln(acc, s_par, g);
    stats_lds(acc, s_red, wv, g, q);
    pack_lds(acc, s_y, wv, g, q);    // own band
    burst_out(s_y, out, tile, a, t); // own band (intra-wave order suffices)
    __syncthreads();                 // cluster writes / reset drift
  }

  if (t < 128) {
    float S = s_red[0][0][t] + s_red[0][1][t] + s_red[0][2][t] + s_red[0][3][t];
    float Q = s_red[1][0][t] + s_red[1][1][t] + s_red[1][2][t] + s_red[1][3][t];
    atomicAdd(statS + a * 128 + t, S);
    atomicAdd(statQ + a * 128 + t, Q);
  }
}

// ---------- pass 2: burst y1 -> LDS, h1=BN1+ReLU, GEMM2+LN2 -> y2 (in place), 1 barrier/tile ----
__launch_bounds__(256, 2)
__global__ void pass2_kernel(const float* __restrict__ b2, const float* __restrict__ ln2g,
                             const float* __restrict__ ln2b,
                             const uint8_t* __restrict__ w2img,
                             const float2* __restrict__ bn1,
                             float* __restrict__ statS, float* __restrict__ statQ,
                             float* __restrict__ out) {
  __shared__ __align__(16) uint8_t s_w2[32768];
  __shared__ __align__(16) uint8_t s_y[32768];
  __shared__ float s_par[384];
  __shared__ __align__(16) float2 s_bnc[128];
  __shared__ float s_red[2][4][128];

  const int t = threadIdx.x;
  const int wv = t >> 6, l = t & 63, g = l >> 4, q = l & 15;
  int a, sub;
  work_id(blockIdx.x, a, sub);

  const uint8_t* w2src = w2img + (size_t)a * 32768;
  #pragma unroll
  for (int i = 0; i < 8; ++i) ((u32v4*)s_w2)[t + 256 * i] = ((const u32v4*)w2src)[t + 256 * i];
  if (t < 128) {
    s_par[PB + t] = b2[a * 128 + t];
    s_par[PG + t] = ln2g[a * 128 + t];
    s_par[PBT + t] = ln2b[a * 128 + t];
    s_bnc[t] = bn1[a * 128 + t];
  }
  #pragma unroll
  for (int i = 0; i < 4; ++i) ((float*)s_red)[t + 256 * i] = 0.f;
  __syncthreads();

  for (int tt = 0; tt < 4; ++tt) {
    const int tile = sub * 4 + tt;

    burst_in(s_y, out, tile, a, t);  // own band

    f32x4 acc[8][2];
    #pragma unroll
    for (int mf = 0; mf < 8; ++mf) { acc[mf][0] = f4z(); acc[mf][1] = f4z(); }

    #pragma unroll
    for (int ks2 = 0; ks2 < 4; ++ks2) {
      const int k0 = 32 * ks2 + 8 * g;
      f32x4 cf[4];
      #pragma unroll
      for (int i = 0; i < 4; ++i)
        cf[i] = *(const f32x4*)((const uint8_t*)s_bnc + k0 * 8 + 16 * i);
      bf16x8 bfr[2];
      #pragma unroll
      for (int nf = 0; nf < 2; ++nf) {
        uint32_t row = 32 * wv + 16 * nf + q;   // own band
        u32v4 yv = *(const u32v4*)(s_y + row * 256 + SWZ(row, 64 * ks2 + 16 * g));
        bfr[nf] = bn_frag(yv, cf);
      }
      #pragma unroll
      for (int mf = 0; mf < 8; ++mf) {
        uint32_t r = 16 * mf + q;
        uint32_t cb = ((uint32_t)(64 * ks2 + 16 * g)) ^ ((r & 7u) << 4);
        bf16x8 af = ld_frag(s_w2 + r * 256 + cb);
        acc[mf][0] = mfma16(af, bfr[0], acc[mf][0]);
        acc[mf][1] = mfma16(af, bfr[1], acc[mf][1]);
      }
    }

    bias_ln(acc, s_par, g);
    stats_lds(acc, s_red, wv, g, q);
    pack_lds(acc, s_y, wv, g, q);    // overwrite own band with y2 (own reads done)
    burst_out(s_y, out, tile, a, t); // own band
    __syncthreads();                 // cluster writes / reset drift
  }

  if (t < 128) {
    float S = s_red[0][0][t] + s_red[0][1][t] + s_red[0][2][t] + s_red[0][3][t];
    float Q = s_red[1][0][t] + s_red[1][1][t] + s_red[1][2][t] + s_red[1][3][t];
    atomicAdd(statS + a * 128 + t, S);
    atomicAdd(statQ + a * 128 + t, Q);
  }
}

// ---------- pass 3: burst y2 -> LDS, h2=BN2+ReLU, GEMM3 MFMA, softmax, band-private store ----------
__launch_bounds__(256, 3)
__global__ void pass3_kernel(const int* __restrict__ nidx, const float* __restrict__ boutp,
                             const uint8_t* __restrict__ woimg,
                             const float2* __restrict__ bn2,
                             float* __restrict__ out) {
  __shared__ __align__(16) uint8_t s_buf[43008];  // [0,32768): y-tile; whole: s_out[128][84] f32
  __shared__ __align__(16) uint8_t s_wo[4096];
  __shared__ __align__(16) float2 s_bnc[128];
  __shared__ float s_bout[16];

  uint8_t* s_y = s_buf;
  float* s_out = (float*)s_buf;

  const int t = threadIdx.x;
  const int wv = t >> 6, l = t & 63, g = l >> 4, q = l & 15;
  int a, sub;
  work_id(blockIdx.x, a, sub);

  const int r9 = a / 9, c9 = a - 9 * r9;
  const int deg = 1 + (r9 > 0) + (r9 < 8) + (c9 > 0) + (c9 < 8);
  int nid[5];
  #pragma unroll
  for (int d = 0; d < 5; ++d) nid[d] = __builtin_amdgcn_readfirstlane(nidx[a * 5 + d]);

  ((u32v4*)s_wo)[t] = ((const u32v4*)(woimg + (size_t)a * 4096))[t];
  if (t < 128) s_bnc[t] = bn2[a * 128 + t];
  if (t < 16) s_bout[t] = (t < 5) ? boutp[a * 5 + t] : 0.f;
  __syncthreads();

  // hoist Wout A-frags (tile-invariant)
  bf16x8 afr[4];
  #pragma unroll
  for (int ks2 = 0; ks2 < 4; ++ks2) {
    uint32_t cb = ((uint32_t)(64 * ks2 + 16 * g)) ^ (((uint32_t)q & 7u) << 4);
    afr[ks2] = ld_frag(s_wo + q * 256 + cb);
  }

  for (int tt = 0; tt < 4; ++tt) {
    const int tile = sub * 4 + tt;

    burst_in(s_y, out, tile, a, t);  // own band

    f32x4 accd[2];
    accd[0] = f4z(); accd[1] = f4z();

    #pragma unroll
    for (int ks2 = 0; ks2 < 4; ++ks2) {
      const int k0 = 32 * ks2 + 8 * g;
      f32x4 cf[4];
      #pragma unroll
      for (int i = 0; i < 4; ++i)
        cf[i] = *(const f32x4*)((const uint8_t*)s_bnc + k0 * 8 + 16 * i);
      #pragma unroll
      for (int nf = 0; nf < 2; ++nf) {
        uint32_t row = 32 * wv + 16 * nf + q;   // own band
        u32v4 yv = *(const u32v4*)(s_y + row * 256 + SWZ(row, 64 * ks2 + 16 * g));
        accd[nf] = mfma16(afr[ks2], bn_frag(yv, cf), accd[nf]);
      }
    }

    // + bout, collect d4 from the g^1 row-group, softmax over valid d
    #pragma unroll
    for (int nf = 0; nf < 2; ++nf) {
      #pragma unroll
      for (int rg = 0; rg < 4; ++rg) accd[nf][rg] += s_bout[4 * g + rg];
    }
    float d4[2];
    d4[0] = __shfl_xor(accd[0][0], 16);
    d4[1] = __shfl_xor(accd[1][0], 16);

    float p[2][5];
    #pragma unroll
    for (int nf = 0; nf < 2; ++nf) {
      float v[5] = {accd[nf][0], accd[nf][1], accd[nf][2], accd[nf][3], d4[nf]};
      float mx = v[0];
      #pragma unroll
      for (int d = 1; d < 5; ++d)
        if (d < deg) mx = fmaxf(mx, v[d]);
      float den = 0.f;
      #pragma unroll
      for (int d = 0; d < 5; ++d) {
        float e = (d < deg) ? __expf(v[d] - mx) : 0.f;
        p[nf][d] = e;
        den += e;
      }
      float inv = 1.f / den;
      #pragma unroll
      for (int d = 0; d < 5; ++d) p[nf][d] *= inv;
    }

    // hand nf=1 row to g==2 lanes
    float p5[5];
    #pragma unroll
    for (int d = 0; d < 5; ++d) {
      float pr = __shfl_xor(p[1][d], 32);
      p5[d] = (g == 0) ? p[0][d] : pr;
    }

    __syncthreads();  // all waves done with s_y; s_buf becomes s_out (bands overlap across waves)

    // per-wave epilogue on own 32-row band of s_out[128][84]
    {
      uint8_t* band = (uint8_t*)s_out + (size_t)wv * 10752;  // 32*84*4
      for (int i = l; i < 672; i += 64) {
        u32v4 z; z[0] = 0u; z[1] = 0u; z[2] = 0u; z[3] = 0u;
        *(u32v4*)(band + (size_t)i * 16) = z;
      }
      if (g == 0 || g == 2) {
        const int row = 32 * wv + ((g == 2) ? 16 : 0) + q;
        #pragma unroll
        for (int d = 0; d < 5; ++d)
          if (d < deg) s_out[row * 84 + nid[d]] = p5[d];
      }
      const size_t obase = (size_t)(tile * 128) * 6561 + (size_t)a * 81;
      for (int i = l; i < 32 * 81; i += 64) {
        int rr = i / 81;
        int n = i - rr * 81;
        int row = 32 * wv + rr;
        out[obase + (size_t)row * 6561 + n] = s_out[row * 84 + n];
      }
    }

    __syncthreads();  // epilogue done before next tile's burst_in aliases s_buf
  }
}

extern "C" void kernel_launch(void* const* d_in, const int* in_sizes, int n_in,
                              void* d_out, int out_size, void* d_ws, size_t ws_size,
                              hipStream_t stream) {
  (void)in_sizes; (void)n_in; (void)out_size; (void)ws_size;
  const float* obs = (const float*)d_in[0];
  const int* nidx = (const int*)d_in[1];
  // d_in[2] = neigh_mask (derived structurally)
  const float* W1 = (const float*)d_in[3];
  const float* b1 = (const float*)d_in[4];
  const float* ln1g = (const float*)d_in[5];
  const float* ln1b = (const float*)d_in[6];
  const float* bnb1 = (const float*)d_in[7];
  const float* W2 = (const float*)d_in[8];
  const float* b2 = (const float*)d_in[9];
  const float* ln2g = (const float*)d_in[10];
  const float* ln2b = (const float*)d_in[11];
  const float* bnb2 = (const float*)d_in[12];
  const float* Wout = (const float*)d_in[13];
  const float* bout = (const float*)d_in[14];
  float* out = (float*)d_out;
  uint8_t* ws = (uint8_t*)d_ws;

  // ws layout (regionA is time-shared: zimgT during pass1, then w2img+woimg):
  uint8_t* w1img   = ws;                            // 1,327,104
  uint8_t* globimg = ws + 1327104;                  // 1,572,864
  uint8_t* regionA = ws + 2899968;                  // 5,308,416
  unsigned short* zimgT = (unsigned short*)regionA; //   (pass1)
  uint8_t* w2img = regionA;                         //   (pass2) 2,654,208
  uint8_t* woimg = regionA + 2654208;               //   (pass3)   331,776
  float* statS = (float*)(ws + 8208384);            //    41,472
  float* statQ = (float*)(ws + 8249856);            //    41,472
  float2* bn1 = (float2*)(ws + 8291328);            //    82,944
  float2* bn2 = (float2*)(ws + 8374272);            //    82,944
  // total ws use: 8,457,216 B (proven available)

  prep_w1<<<N_AG, 256, 0, stream>>>(W1, w1img);
  prep_obs<<<64, 256, 0, stream>>>(obs, globimg);
  prep_zimgT<<<128, 256, 0, stream>>>(obs, zimgT);
  hipMemsetAsync(statS, 0, 2 * 41472, stream);

  pass1_kernel<<<N_AG * 32, 256, 0, stream>>>(nidx, b1, ln1g, ln1b, w1img, globimg, zimgT,
                                              statS, statQ, out);
  reduce_bn<<<N_AG, 128, 0, stream>>>(statS, statQ, bnb1, bn1);

  prep_w2wo<<<N_AG, 256, 0, stream>>>(W2, Wout, w2img, woimg);  // overwrites zimgT (pass1 done)
  hipMemsetAsync(statS, 0, 2 * 41472, stream);

  pass2_kernel<<<N_AG * 32, 256, 0, stream>>>(b2, ln2g, ln2b, w2img, bn1,
                                              statS, statQ, out);
  reduce_bn<<<N_AG, 128, 0, stream>>>(statS, statQ, bnb2, bn2);

  pass3_kernel<<<N_AG * 32, 256, 0, stream>>>(nidx, bout, woimg, bn2, out);
}

// Round 14
// 754.441 us; speedup vs baseline: 4.7266x; 1.0037x over previous
//
#include <hip/hip_runtime.h>
#include <stdint.h>
#include <stddef.h>

#define N_AG 81

typedef __bf16 bf16x8 __attribute__((ext_vector_type(8)));
typedef float f32x4 __attribute__((ext_vector_type(4)));
typedef uint32_t u32v4 __attribute__((ext_vector_type(4)));
typedef uint32_t u32v2 __attribute__((ext_vector_type(2)));

// s_par layout (float idx): [0,128) bias, [128,256) ln_gamma, [256,384) ln_beta
#define PB 0
#define PG 128
#define PBT 256

// LDS y-tile swizzle: linear byte offset 'off' within a 256B row
#define SWZ(row, off) ((uint32_t)(off) ^ (((uint32_t)(row) & 7u) << 4))

__device__ __forceinline__ unsigned short b2u(__bf16 h) {
  return __builtin_bit_cast(unsigned short, h);
}

__device__ __forceinline__ f32x4 f4z() { f32x4 v; v[0]=0.f; v[1]=0.f; v[2]=0.f; v[3]=0.f; return v; }

__device__ __forceinline__ bf16x8 ld_frag(const uint8_t* p) {
  u32v4 v = *(const u32v4*)p;
  return __builtin_bit_cast(bf16x8, v);
}

__device__ __forceinline__ f32x4 mfma16(bf16x8 a, bf16x8 b, f32x4 c) {
  return __builtin_amdgcn_mfma_f32_16x16x32_bf16(a, b, c, 0, 0, 0);
}

// XCD-chunked work mapping (r13): bid%8 = XCD, each owns 4 subs x 81 agents.
__device__ __forceinline__ void work_id(int bid, int& a, int& sub) {
  int w = (bid & 7) * 324 + (bid >> 3);
  a = w % N_AG;
  sub = w / N_AG;
}

// y slot for (batch row b, agent a): 256B window inside out[b][a][:], 64B-aligned.
__device__ __forceinline__ uint8_t* yslot(float* out, int b, int a) {
  size_t base = (size_t)b * 26244 + (size_t)a * 324;
  uint32_t pad = (uint32_t)(64 - (base & 63)) & 63u;
  return (uint8_t*)out + base + pad;
}

// butterfly sum over the 16 lanes of a DPP row (q-dimension); all lanes get the sum.
__device__ __forceinline__ float wave16_sum(float v) {
  v += __builtin_bit_cast(float, __builtin_amdgcn_update_dpp(0, __builtin_bit_cast(int, v), 0xB1, 0xF, 0xF, true));
  v += __builtin_bit_cast(float, __builtin_amdgcn_update_dpp(0, __builtin_bit_cast(int, v), 0x4E, 0xF, 0xF, true));
  v += __builtin_bit_cast(float, __builtin_amdgcn_update_dpp(0, __builtin_bit_cast(int, v), 0x141, 0xF, 0xF, true));
  v += __builtin_bit_cast(float, __builtin_amdgcn_update_dpp(0, __builtin_bit_cast(int, v), 0x140, 0xF, 0xF, true));
  return v;
}

__device__ __forceinline__ bf16x8 mk_frag(const unsigned short (&us)[8]) {
  u32v4 pk;
  pk[0] = (uint32_t)us[0] | ((uint32_t)us[1] << 16);
  pk[1] = (uint32_t)us[2] | ((uint32_t)us[3] << 16);
  pk[2] = (uint32_t)us[4] | ((uint32_t)us[5] << 16);
  pk[3] = (uint32_t)us[6] | ((uint32_t)us[7] << 16);
  return __builtin_bit_cast(bf16x8, pk);
}

// BN+ReLU applied to 8 bf16 y-values (one 16B word) with packed (scale,shift) coefs.
__device__ __forceinline__ bf16x8 bn_frag(u32v4 yv, const f32x4 (&cf)[4]) {
  bf16x8 r;
  #pragma unroll
  for (int j = 0; j < 8; ++j) {
    uint32_t us = (j & 1) ? (yv[j >> 1] >> 16) : (yv[j >> 1] & 0xffffu);
    float f = __builtin_bit_cast(float, us << 16);
    float h = fmaf(f, cf[j >> 1][(j & 1) * 2], cf[j >> 1][(j & 1) * 2 + 1]);
    r[j] = (__bf16)fmaxf(h, 0.f);
  }
  return r;
}

// fused bias + layernorm, 2 batch-cols per lane (pass2/3 128-row tiles)
__device__ __forceinline__ void bias_ln(f32x4 (&acc)[8][2], const float* s_par, int g) {
  #pragma unroll
  for (int nf = 0; nf < 2; ++nf) {
    float s = 0.f, qs = 0.f;
    #pragma unroll
    for (int mf = 0; mf < 8; ++mf) {
      #pragma unroll
      for (int rg = 0; rg < 4; ++rg) {
        float tv = acc[mf][nf][rg] + s_par[PB + 16 * mf + 4 * g + rg];
        acc[mf][nf][rg] = tv;
        s += tv;
        qs = fmaf(tv, tv, qs);
      }
    }
    s += __shfl_xor(s, 16);  s += __shfl_xor(s, 32);
    qs += __shfl_xor(qs, 16); qs += __shfl_xor(qs, 32);
    float mu = s * (1.f / 128.f);
    float var = qs * (1.f / 128.f) - mu * mu;
    float rstd = rsqrtf(var + 1e-12f);
    #pragma unroll
    for (int mf = 0; mf < 8; ++mf) {
      #pragma unroll
      for (int rg = 0; rg < 4; ++rg) {
        int o = 16 * mf + 4 * g + rg;
        acc[mf][nf][rg] = (acc[mf][nf][rg] - mu) * rstd * s_par[PG + o] + s_par[PBT + o];
      }
    }
  }
}

// fused bias + layernorm, single batch-col per lane (pass1 64-row halves)
__device__ __forceinline__ void bias_ln1(f32x4 (&acc)[8], const float* s_par, int g) {
  float s = 0.f, qs = 0.f;
  #pragma unroll
  for (int mf = 0; mf < 8; ++mf) {
    #pragma unroll
    for (int rg = 0; rg < 4; ++rg) {
      float tv = acc[mf][rg] + s_par[PB + 16 * mf + 4 * g + rg];
      acc[mf][rg] = tv;
      s += tv;
      qs = fmaf(tv, tv, qs);
    }
  }
  s += __shfl_xor(s, 16);  s += __shfl_xor(s, 32);
  qs += __shfl_xor(qs, 16); qs += __shfl_xor(qs, 32);
  float mu = s * (1.f / 128.f);
  float var = qs * (1.f / 128.f) - mu * mu;
  float rstd = rsqrtf(var + 1e-12f);
  #pragma unroll
  for (int mf = 0; mf < 8; ++mf) {
    #pragma unroll
    for (int rg = 0; rg < 4; ++rg) {
      int o = 16 * mf + 4 * g + rg;
      acc[mf][rg] = (acc[mf][rg] - mu) * rstd * s_par[PG + o] + s_par[PBT + o];
    }
  }
}

// stats accumulation, 2-col version (pass2)
__device__ __forceinline__ void stats_lds(const f32x4 (&acc)[8][2],
                                          float (&s_red)[2][4][128],
                                          int wv, int g, int q) {
  #pragma unroll
  for (int mf = 0; mf < 8; ++mf) {
    #pragma unroll
    for (int rg = 0; rg < 4; ++rg) {
      float a0v = acc[mf][0][rg], a1v = acc[mf][1][rg];
      float s = a0v + a1v;
      float qq = fmaf(a0v, a0v, a1v * a1v);
      s = wave16_sum(s);
      qq = wave16_sum(qq);
      if (q == 0) {
        int o = 16 * mf + 4 * g + rg;
        s_red[0][wv][o] += s;
        s_red[1][wv][o] += qq;
      }
    }
  }
}

// stats accumulation, 1-col version (pass1)
__device__ __forceinline__ void stats_lds1(const f32x4 (&acc)[8],
                                           float (&s_red)[2][4][128],
                                           int wv, int g, int q) {
  #pragma unroll
  for (int mf = 0; mf < 8; ++mf) {
    #pragma unroll
    for (int rg = 0; rg < 4; ++rg) {
      float s = acc[mf][rg];
      float qq = s * s;
      s = wave16_sum(s);
      qq = wave16_sum(qq);
      if (q == 0) {
        int o = 16 * mf + 4 * g + rg;
        s_red[0][wv][o] += s;
        s_red[1][wv][o] += qq;
      }
    }
  }
}

// pack accumulator tile (bf16) into LDS y-tile, 2-col (pass2); wave-private band.
__device__ __forceinline__ void pack_lds(const f32x4 (&acc)[8][2], uint8_t* s_y,
                                         int wv, int g, int q) {
  #pragma unroll
  for (int nf = 0; nf < 2; ++nf) {
    uint32_t row = 32 * wv + 16 * nf + q;
    #pragma unroll
    for (int mf = 0; mf < 8; ++mf) {
      u32v2 pk;
      pk[0] = (uint32_t)b2u((__bf16)acc[mf][nf][0]) | ((uint32_t)b2u((__bf16)acc[mf][nf][1]) << 16);
      pk[1] = (uint32_t)b2u((__bf16)acc[mf][nf][2]) | ((uint32_t)b2u((__bf16)acc[mf][nf][3]) << 16);
      *(u32v2*)(s_y + row * 256 + SWZ(row, 32 * mf + 8 * g)) = pk;
    }
  }
}

// pack accumulator (bf16) into LDS y-tile row 16wv+q, 1-col (pass1)
__device__ __forceinline__ void pack_lds1(const f32x4 (&acc)[8], uint8_t* s_y,
                                          int wv, int g, int q) {
  uint32_t row = 16 * wv + q;
  #pragma unroll
  for (int mf = 0; mf < 8; ++mf) {
    u32v2 pk;
    pk[0] = (uint32_t)b2u((__bf16)acc[mf][0]) | ((uint32_t)b2u((__bf16)acc[mf][1]) << 16);
    pk[1] = (uint32_t)b2u((__bf16)acc[mf][2]) | ((uint32_t)b2u((__bf16)acc[mf][3]) << 16);
    *(u32v2*)(s_y + row * 256 + SWZ(row, 32 * mf + 8 * g)) = pk;
  }
}

// burst copy LDS y-tile -> global slots, 128-row tile (thread: 128B half-slot; own band)
__device__ __forceinline__ void burst_out(const uint8_t* s_y, float* out, int tile, int a, int t) {
  const int row = t >> 1, half = t & 1;
  uint8_t* sp = yslot(out, tile * 128 + row, a) + half * 128;
  #pragma unroll
  for (int j = 0; j < 8; ++j) {
    u32v4 v = *(const u32v4*)(s_y + row * 256 + SWZ(row, half * 128 + 16 * j));
    *(u32v4*)(sp + 16 * j) = v;
  }
}

// burst copy LDS y-tile -> global slots, 64-row half (thread: 64B quarter-slot; own band)
__device__ __forceinline__ void burst_out64(const uint8_t* s_y, float* out, int base, int a, int t) {
  const int row = t >> 2, qt = t & 3;
  uint8_t* sp = yslot(out, base + row, a) + qt * 64;
  #pragma unroll
  for (int j = 0; j < 4; ++j) {
    u32v4 v = *(const u32v4*)(s_y + row * 256 + SWZ(row, qt * 64 + 16 * j));
    *(u32v4*)(sp + 16 * j) = v;
  }
}

// prefetch this thread's 128B half-slot into registers (128-row tiles)
__device__ __forceinline__ void load_yregs(u32v4 (&yr)[8], const float* out, int tile, int a, int t) {
  const int row = t >> 1, half = t & 1;
  const uint8_t* sp = yslot((float*)out, tile * 128 + row, a) + half * 128;
  #pragma unroll
  for (int j = 0; j < 8; ++j) yr[j] = *(const u32v4*)(sp + 16 * j);
}

// write prefetched registers into LDS y-tile (own band)
__device__ __forceinline__ void write_yregs(uint8_t* s_y, const u32v4 (&yr)[8], int t) {
  const int row = t >> 1, half = t & 1;
  #pragma unroll
  for (int j = 0; j < 8; ++j)
    *(u32v4*)(s_y + row * 256 + SWZ(row, half * 128 + 16 * j)) = yr[j];
}

// ---------- prep kernels ----------
__global__ void prep_w1(const float* __restrict__ W1, uint8_t* __restrict__ w1img,
                        float* __restrict__ statS, float* __restrict__ statQ) {
  const int a = blockIdx.x, t = threadIdx.x;
  for (int i = t; i < 128 * 64; i += 256) {
    int o = i & 127, kk = i >> 7;
    float v;
    if (kk < 48)      v = W1[((size_t)a * 58 + (10 + kk)) * 128 + o];
    else if (kk < 58) v = W1[((size_t)a * 58 + (kk - 48)) * 128 + o];
    else              v = 0.f;
    uint32_t cb = 2u * kk;
    uint32_t phys = o * 128 + (((cb & ~15u) ^ (((uint32_t)o & 7u) << 4)) | (cb & 15u));
    *(unsigned short*)(w1img + (size_t)a * 16384 + phys) = b2u((__bf16)v);
  }
  if (t < 128) {
    statS[a * 128 + t] = 0.f;
    statQ[a * 128 + t] = 0.f;
  }
}

__global__ void prep_w2wo(const float* __restrict__ W2, const float* __restrict__ Wout,
                          uint8_t* __restrict__ w2img, uint8_t* __restrict__ woimg) {
  const int a = blockIdx.x, t = threadIdx.x;
  for (int i = t; i < 128 * 128; i += 256) {
    int o = i & 127, kk = i >> 7;
    float v = W2[((size_t)a * 128 + kk) * 128 + o];
    uint32_t cb = 2u * kk;
    uint32_t phys = o * 256 + (((cb & ~15u) ^ (((uint32_t)o & 7u) << 4)) | (cb & 15u));
    *(unsigned short*)(w2img + (size_t)a * 32768 + phys) = b2u((__bf16)v);
  }
  for (int i = t; i < 16 * 128; i += 256) {
    int k = i & 127, d = i >> 7;
    float v = (d < 5) ? Wout[((size_t)a * 128 + k) * 5 + d] : 0.f;
    uint32_t cb = 2u * k;
    uint32_t phys = d * 256 + (((cb & ~15u) ^ (((uint32_t)d & 7u) << 4)) | (cb & 15u));
    *(unsigned short*)(woimg + (size_t)a * 4096 + phys) = b2u((__bf16)v);
  }
}

__global__ void prep_obs(const float* __restrict__ obs, uint8_t* __restrict__ globimg) {
  const int row = blockIdx.x * 256 + threadIdx.x;
  if (row >= 16384) return;
  const float* orow = obs + (size_t)row * 210;
  uint8_t* dst = globimg + (size_t)row * 96;
  #pragma unroll
  for (int c = 0; c < 6; ++c) {
    u32v4 pk;
    #pragma unroll
    for (int e = 0; e < 4; ++e) {
      pk[e] = (uint32_t)b2u((__bf16)orow[8 * c + 2 * e]) |
              ((uint32_t)b2u((__bf16)orow[8 * c + 2 * e + 1]) << 16);
    }
    *(u32v4*)(dst + 16 * c) = pk;
  }
}

// transposed bf16 zone image: zimgT[n][b], n in [0,162) = obs cols 48..209.
__global__ void prep_zimgT(const float* __restrict__ obs, unsigned short* __restrict__ zimgT) {
  __shared__ unsigned short lt[128][164];
  const int t = threadIdx.x;
  const int b0 = blockIdx.x * 128;
  for (int i = t; i < 128 * 162; i += 256) {
    int br = i / 162, n = i - 162 * br;
    lt[br][n] = b2u((__bf16)obs[(size_t)(b0 + br) * 210 + 48 + n]);
  }
  __syncthreads();
  for (int i = t; i < 162 * 128; i += 256) {
    int n = i >> 7, br = i & 127;
    zimgT[(size_t)n * 16384 + b0 + br] = lt[br][n];
  }
}

// finalize BN coefs from atomic sums, then zero the stat buffers for the next user.
__global__ void reduce_bn(float* __restrict__ S, float* __restrict__ Q,
                          const float* __restrict__ beta, float2* __restrict__ bn) {
  const int a = blockIdx.x, k = threadIdx.x;
  float mu = S[a * 128 + k] * (1.f / 16384.f);
  float var = Q[a * 128 + k] * (1.f / 16384.f) - mu * mu;
  float rs = rsqrtf(var + 1e-3f);  // BN_EPS
  bn[a * 128 + k] = make_float2(rs, beta[a * 128 + k] - mu * rs);
  S[a * 128 + k] = 0.f;
  Q[a * 128 + k] = 0.f;
}

// ---------- pass 1: GEMM1 + LN1 -> y1 slots + BN1 stats (64-row halves, 4 blocks/CU) ----------
__launch_bounds__(256, 4)
__global__ void pass1_kernel(const int* __restrict__ nidx,
                             const float* __restrict__ b1, const float* __restrict__ ln1g,
                             const float* __restrict__ ln1b,
                             const uint8_t* __restrict__ w1img,
                             const uint8_t* __restrict__ globimg,
                             const unsigned short* __restrict__ zimgT,
                             float* __restrict__ statS, float* __restrict__ statQ,
                             float* __restrict__ out) {
  __shared__ __align__(16) uint8_t s_w1[16384];
  __shared__ __align__(16) uint8_t s_y[16384];
  __shared__ float s_par[384];
  __shared__ float s_red[2][4][128];

  const int t = threadIdx.x;
  const int wv = t >> 6, l = t & 63, g = l >> 4, q = l & 15;
  int a, sub;
  work_id(blockIdx.x, a, sub);

  const int r9 = a / 9, c9 = a - 9 * r9;
  const int deg = 1 + (r9 > 0) + (r9 < 8) + (c9 > 0) + (c9 < 8);
  int nid[5];
  #pragma unroll
  for (int d = 0; d < 5; ++d) nid[d] = __builtin_amdgcn_readfirstlane(nidx[a * 5 + d]);

  const uint8_t* w1src = w1img + (size_t)a * 16384;
  #pragma unroll
  for (int i = 0; i < 4; ++i) ((u32v4*)s_w1)[t + 256 * i] = ((const u32v4*)w1src)[t + 256 * i];
  if (t < 128) {
    s_par[PB + t] = b1[a * 128 + t];
    s_par[PG + t] = ln1g[a * 128 + t];
    s_par[PBT + t] = ln1b[a * 128 + t];
  }
  #pragma unroll
  for (int i = 0; i < 4; ++i) ((float*)s_red)[t + 256 * i] = 0.f;
  __syncthreads();

  for (int hh = 0; hh < 8; ++hh) {
    const int base = sub * 512 + hh * 64;
    const int brow = base + 16 * wv + q;

    bf16x8 bfr[2];
    #pragma unroll
    for (int ks = 0; ks < 2; ++ks) {
      if (ks == 1 && g >= 2) {
        unsigned short us[8];
        if (g == 2) {
          #pragma unroll
          for (int e = 0; e < 5; ++e)
            us[e] = (e < deg) ? zimgT[(size_t)nid[e] * 16384 + brow] : (unsigned short)0;
          #pragma unroll
          for (int e = 0; e < 3; ++e)
            us[5 + e] = (e < deg) ? zimgT[(size_t)(81 + nid[e]) * 16384 + brow] : (unsigned short)0;
        } else {
          us[0] = (3 < deg) ? zimgT[(size_t)(81 + nid[3]) * 16384 + brow] : (unsigned short)0;
          us[1] = (4 < deg) ? zimgT[(size_t)(81 + nid[4]) * 16384 + brow] : (unsigned short)0;
          #pragma unroll
          for (int e = 2; e < 8; ++e) us[e] = 0;
        }
        bfr[ks] = mk_frag(us);
      } else {
        bfr[ks] = *(const bf16x8*)(globimg + (size_t)brow * 96 + (32 * ks + 8 * g) * 2);
      }
    }

    f32x4 acc[8];
    #pragma unroll
    for (int mf = 0; mf < 8; ++mf) acc[mf] = f4z();
    #pragma unroll
    for (int ks = 0; ks < 2; ++ks) {
      #pragma unroll
      for (int mf = 0; mf < 8; ++mf) {
        uint32_t r = 16 * mf + q;
        uint32_t cb = ((uint32_t)(64 * ks + 16 * g)) ^ ((r & 7u) << 4);
        bf16x8 af = ld_frag(s_w1 + r * 128 + cb);
        acc[mf] = mfma16(af, bfr[ks], acc[mf]);
      }
    }

    bias_ln1(acc, s_par, g);
    stats_lds1(acc, s_red, wv, g, q);
    pack_lds1(acc, s_y, wv, g, q);       // own 16-row band
    burst_out64(s_y, out, base, a, t);   // own band
    __syncthreads();                     // cluster writes
  }

  if (t < 128) {
    float S = s_red[0][0][t] + s_red[0][1][t] + s_red[0][2][t] + s_red[0][3][t];
    float Q = s_red[1][0][t] + s_red[1][1][t] + s_red[1][2][t] + s_red[1][3][t];
    atomicAdd(statS + a * 128 + t, S);
    atomicAdd(statQ + a * 128 + t, Q);
  }
}

// ---------- pass 2: prefetch y1 -> regs -> LDS, h1=BN1+ReLU, GEMM2+LN2 -> y2 (in place) ----------
__launch_bounds__(256, 2)
__global__ void pass2_kernel(const float* __restrict__ b2, const float* __restrict__ ln2g,
                             const float* __restrict__ ln2b,
                             const uint8_t* __restrict__ w2img,
                             const float2* __restrict__ bn1,
                             float* __restrict__ statS, float* __restrict__ statQ,
                             float* __restrict__ out) {
  __shared__ __align__(16) uint8_t s_w2[32768];
  __shared__ __align__(16) uint8_t s_y[32768];
  __shared__ float s_par[384];
  __shared__ __align__(16) float2 s_bnc[128];
  __shared__ float s_red[2][4][128];

  const int t = threadIdx.x;
  const int wv = t >> 6, l = t & 63, g = l >> 4, q = l & 15;
  int a, sub;
  work_id(blockIdx.x, a, sub);

  const uint8_t* w2src = w2img + (size_t)a * 32768;
  #pragma unroll
  for (int i = 0; i < 8; ++i) ((u32v4*)s_w2)[t + 256 * i] = ((const u32v4*)w2src)[t + 256 * i];
  if (t < 128) {
    s_par[PB + t] = b2[a * 128 + t];
    s_par[PG + t] = ln2g[a * 128 + t];
    s_par[PBT + t] = ln2b[a * 128 + t];
    s_bnc[t] = bn1[a * 128 + t];
  }
  #pragma unroll
  for (int i = 0; i < 4; ++i) ((float*)s_red)[t + 256 * i] = 0.f;

  u32v4 yreg[8];
  load_yregs(yreg, out, sub * 4, a, t);   // prefetch tile 0 (overlaps staging)
  __syncthreads();

  for (int tt = 0; tt < 4; ++tt) {
    const int tile = sub * 4 + tt;

    write_yregs(s_y, yreg, t);            // own band (waits its own loads)
    if (tt < 3) load_yregs(yreg, out, tile + 1, a, t);  // prefetch next under compute

    f32x4 acc[8][2];
    #pragma unroll
    for (int mf = 0; mf < 8; ++mf) { acc[mf][0] = f4z(); acc[mf][1] = f4z(); }

    #pragma unroll
    for (int ks2 = 0; ks2 < 4; ++ks2) {
      const int k0 = 32 * ks2 + 8 * g;
      f32x4 cf[4];
      #pragma unroll
      for (int i = 0; i < 4; ++i)
        cf[i] = *(const f32x4*)((const uint8_t*)s_bnc + k0 * 8 + 16 * i);
      bf16x8 bfr[2];
      #pragma unroll
      for (int nf = 0; nf < 2; ++nf) {
        uint32_t row = 32 * wv + 16 * nf + q;   // own band
        u32v4 yv = *(const u32v4*)(s_y + row * 256 + SWZ(row, 64 * ks2 + 16 * g));
        bfr[nf] = bn_frag(yv, cf);
      }
      #pragma unroll
      for (int mf = 0; mf < 8; ++mf) {
        uint32_t r = 16 * mf + q;
        uint32_t cb = ((uint32_t)(64 * ks2 + 16 * g)) ^ ((r & 7u) << 4);
        bf16x8 af = ld_frag(s_w2 + r * 256 + cb);
        acc[mf][0] = mfma16(af, bfr[0], acc[mf][0]);
        acc[mf][1] = mfma16(af, bfr[1], acc[mf][1]);
      }
    }

    bias_ln(acc, s_par, g);
    stats_lds(acc, s_red, wv, g, q);
    pack_lds(acc, s_y, wv, g, q);    // overwrite own band with y2 (own reads done)
    burst_out(s_y, out, tile, a, t); // own band
    __syncthreads();                 // cluster writes
  }

  if (t < 128) {
    float S = s_red[0][0][t] + s_red[0][1][t] + s_red[0][2][t] + s_red[0][3][t];
    float Q = s_red[1][0][t] + s_red[1][1][t] + s_red[1][2][t] + s_red[1][3][t];
    atomicAdd(statS + a * 128 + t, S);
    atomicAdd(statQ + a * 128 + t, Q);
  }
}

// ---------- pass 3: prefetch y2 -> regs -> LDS, h2=BN2+ReLU, GEMM3, softmax, band store ----------
__launch_bounds__(256, 3)
__global__ void pass3_kernel(const int* __restrict__ nidx, const float* __restrict__ boutp,
                             const uint8_t* __restrict__ woimg,
                             const float2* __restrict__ bn2,
                             float* __restrict__ out) {
  __shared__ __align__(16) uint8_t s_buf[43008];  // [0,32768): y-tile; whole: s_out[128][84] f32
  __shared__ __align__(16) uint8_t s_wo[4096];
  __shared__ __align__(16) float2 s_bnc[128];
  __shared__ float s_bout[16];

  uint8_t* s_y = s_buf;
  float* s_out = (float*)s_buf;

  const int t = threadIdx.x;
  const int wv = t >> 6, l = t & 63, g = l >> 4, q = l & 15;
  int a, sub;
  work_id(blockIdx.x, a, sub);

  const int r9 = a / 9, c9 = a - 9 * r9;
  const int deg = 1 + (r9 > 0) + (r9 < 8) + (c9 > 0) + (c9 < 8);
  int nid[5];
  #pragma unroll
  for (int d = 0; d < 5; ++d) nid[d] = __builtin_amdgcn_readfirstlane(nidx[a * 5 + d]);

  ((u32v4*)s_wo)[t] = ((const u32v4*)(woimg + (size_t)a * 4096))[t];
  if (t < 128) s_bnc[t] = bn2[a * 128 + t];
  if (t < 16) s_bout[t] = (t < 5) ? boutp[a * 5 + t] : 0.f;

  u32v4 yreg[8];
  load_yregs(yreg, out, sub * 4, a, t);   // prefetch tile 0
  __syncthreads();

  // hoist Wout A-frags (tile-invariant)
  bf16x8 afr[4];
  #pragma unroll
  for (int ks2 = 0; ks2 < 4; ++ks2) {
    uint32_t cb = ((uint32_t)(64 * ks2 + 16 * g)) ^ (((uint32_t)q & 7u) << 4);
    afr[ks2] = ld_frag(s_wo + q * 256 + cb);
  }

  for (int tt = 0; tt < 4; ++tt) {
    const int tile = sub * 4 + tt;

    write_yregs(s_y, yreg, t);            // own band
    if (tt < 3) load_yregs(yreg, out, tile + 1, a, t);  // prefetch next under compute

    f32x4 accd[2];
    accd[0] = f4z(); accd[1] = f4z();

    #pragma unroll
    for (int ks2 = 0; ks2 < 4; ++ks2) {
      const int k0 = 32 * ks2 + 8 * g;
      f32x4 cf[4];
      #pragma unroll
      for (int i = 0; i < 4; ++i)
        cf[i] = *(const f32x4*)((const uint8_t*)s_bnc + k0 * 8 + 16 * i);
      #pragma unroll
      for (int nf = 0; nf < 2; ++nf) {
        uint32_t row = 32 * wv + 16 * nf + q;   // own band
        u32v4 yv = *(const u32v4*)(s_y + row * 256 + SWZ(row, 64 * ks2 + 16 * g));
        accd[nf] = mfma16(afr[ks2], bn_frag(yv, cf), accd[nf]);
      }
    }

    // + bout, collect d4 from the g^1 row-group, softmax over valid d
    #pragma unroll
    for (int nf = 0; nf < 2; ++nf) {
      #pragma unroll
      for (int rg = 0; rg < 4; ++rg) accd[nf][rg] += s_bout[4 * g + rg];
    }
    float d4[2];
    d4[0] = __shfl_xor(accd[0][0], 16);
    d4[1] = __shfl_xor(accd[1][0], 16);

    float p[2][5];
    #pragma unroll
    for (int nf = 0; nf < 2; ++nf) {
      float v[5] = {accd[nf][0], accd[nf][1], accd[nf][2], accd[nf][3], d4[nf]};
      float mx = v[0];
      #pragma unroll
      for (int d = 1; d < 5; ++d)
        if (d < deg) mx = fmaxf(mx, v[d]);
      float den = 0.f;
      #pragma unroll
      for (int d = 0; d < 5; ++d) {
        float e = (d < deg) ? __expf(v[d] - mx) : 0.f;
        p[nf][d] = e;
        den += e;
      }
      float inv = 1.f / den;
      #pragma unroll
      for (int d = 0; d < 5; ++d) p[nf][d] *= inv;
    }

    // hand nf=1 row to g==2 lanes
    float p5[5];
    #pragma unroll
    for (int d = 0; d < 5; ++d) {
      float pr = __shfl_xor(p[1][d], 32);
      p5[d] = (g == 0) ? p[0][d] : pr;
    }

    __syncthreads();  // all waves done with s_y; s_buf becomes s_out

    // per-wave epilogue on own 32-row band of s_out[128][84]
    {
      uint8_t* band = (uint8_t*)s_out + (size_t)wv * 10752;  // 32*84*4
      for (int i = l; i < 672; i += 64) {
        u32v4 z; z[0] = 0u; z[1] = 0u; z[2] = 0u; z[3] = 0u;
        *(u32v4*)(band + (size_t)i * 16) = z;
      }
      if (g == 0 || g == 2) {
        const int row = 32 * wv + ((g == 2) ? 16 : 0) + q;
        #pragma unroll
        for (int d = 0; d < 5; ++d)
          if (d < deg) s_out[row * 84 + nid[d]] = p5[d];
      }
      const size_t obase = (size_t)(tile * 128) * 6561 + (size_t)a * 81;
      for (int i = l; i < 32 * 81; i += 64) {
        int rr = i / 81;
        int n = i - rr * 81;
        int row = 32 * wv + rr;
        out[obase + (size_t)row * 6561 + n] = s_out[row * 84 + n];
      }
    }

    __syncthreads();  // epilogue done before next tile's write_yregs aliases s_buf
  }
}

extern "C" void kernel_launch(void* const* d_in, const int* in_sizes, int n_in,
                              void* d_out, int out_size, void* d_ws, size_t ws_size,
                              hipStream_t stream) {
  (void)in_sizes; (void)n_in; (void)out_size; (void)ws_size;
  const float* obs = (const float*)d_in[0];
  const int* nidx = (const int*)d_in[1];
  // d_in[2] = neigh_mask (derived structurally)
  const float* W1 = (const float*)d_in[3];
  const float* b1 = (const float*)d_in[4];
  const float* ln1g = (const float*)d_in[5];
  const float* ln1b = (const float*)d_in[6];
  const float* bnb1 = (const float*)d_in[7];
  const float* W2 = (const float*)d_in[8];
  const float* b2 = (const float*)d_in[9];
  const float* ln2g = (const float*)d_in[10];
  const float* ln2b = (const float*)d_in[11];
  const float* bnb2 = (const float*)d_in[12];
  const float* Wout = (const float*)d_in[13];
  const float* bout = (const float*)d_in[14];
  float* out = (float*)d_out;
  uint8_t* ws = (uint8_t*)d_ws;

  // ws layout (regionA is time-shared: zimgT during pass1, then w2img+woimg):
  uint8_t* w1img   = ws;                            // 1,327,104
  uint8_t* globimg = ws + 1327104;                  // 1,572,864
  uint8_t* regionA = ws + 2899968;                  // 5,308,416
  unsigned short* zimgT = (unsigned short*)regionA; //   (pass1)
  uint8_t* w2img = regionA;                         //   (pass2) 2,654,208
  uint8_t* woimg = regionA + 2654208;               //   (pass3)   331,776
  float* statS = (float*)(ws + 8208384);            //    41,472
  float* statQ = (float*)(ws + 8249856);            //    41,472
  float2* bn1 = (float2*)(ws + 8291328);            //    82,944
  float2* bn2 = (float2*)(ws + 8374272);            //    82,944
  // total ws use: 8,457,216 B (proven available)

  prep_w1<<<N_AG, 256, 0, stream>>>(W1, w1img, statS, statQ);  // also zeroes stats
  prep_obs<<<64, 256, 0, stream>>>(obs, globimg);
  prep_zimgT<<<128, 256, 0, stream>>>(obs, zimgT);

  pass1_kernel<<<N_AG * 32, 256, 0, stream>>>(nidx, b1, ln1g, ln1b, w1img, globimg, zimgT,
                                              statS, statQ, out);
  reduce_bn<<<N_AG, 128, 0, stream>>>(statS, statQ, bnb1, bn1);  // also zeroes stats

  prep_w2wo<<<N_AG, 256, 0, stream>>>(W2, Wout, w2img, woimg);  // overwrites zimgT (pass1 done)

  pass2_kernel<<<N_AG * 32, 256, 0, stream>>>(b2, ln2g, ln2b, w2img, bn1,
                                              statS, statQ, out);
  reduce_bn<<<N_AG, 128, 0, stream>>>(statS, statQ, bnb2, bn2);

  pass3_kernel<<<N_AG * 32, 256, 0, stream>>>(nidx, bout, woimg, bn2, out);
}